// Round 7
// baseline (738.128 us; speedup 1.0000x reference)
//
#include <hip/hip_runtime.h>
#include <hip/hip_bf16.h>
#include <math.h>

#define E_DIM 512
#define H_DIM 1024
#define V_DIM 50257
#define NSTEPS 19
#define NB_F32 1024      // fp32 logits blocks (4 waves each)
#define NB_LOG 512       // int8 logits blocks (8 waves each) -> 4096 waves
#define RPW 13           // rows per wave (4096*13 = 53248 >= V)
#define RPB 104          // rows per scan block (8*13)
#define NB_GATES 256
#define BL_CAP 256
#define CAND_CAP 2048
#define PF 4             // row prefetch depth (static indices only)

// ---- workspace layout (bytes), NO overlaps, 16B-aligned ----
#define OFF_X      0          // 512 f
#define OFF_H      4096       // 1024 f
#define OFF_C      8192       // 1024 f (ping)
#define OFF_C2     12288      // 1024 f (pong)
#define OFF_GATES  16384      // 4096 f
#define OFF_HN     32768      // 1 f
#define OFF_PART   33024      // 1024 u64 (ends 41216)
#define OFF_PBLOCK 41216      // 512 float2 (ends 45312)
#define OFF_SNB    57344      // 50257 float4 {scale, nrm, bias, 0} (ends 861456)
#define OFF_LE     861456     // 50257 float2 {L, e} (ends 1263512)
#define OFF_WBI    1263616    // int8 W_lin, 50257*1024 B (ends 52726784)
#define WS_NEEDED  52726784ull

__device__ inline unsigned fmap(float f) {
    unsigned u = __float_as_uint(f);
    return (u & 0x80000000u) ? ~u : (u | 0x80000000u);
}
__device__ inline unsigned long long packmax(float s, int row) {
    return ((unsigned long long)fmap(s) << 32) | (unsigned)(0xFFFFFFFFu - (unsigned)row);
}
__device__ inline float sigm(float v) { return 1.0f / (1.0f + expf(-v)); }

// h fragment layout "hr4": hr[j] = h4[lane + 64j] (covers all 1024)
__device__ inline void load_h4(const float* __restrict__ h, float4 hr[4], int lane) {
    const float4* h4 = (const float4*)h;
#pragma unroll
    for (int j = 0; j < 4; ++j) hr[j] = h4[lane + 64 * j];
}
// exact fp32 wave-collective row dot (hr4 layout, broadcast result)
__device__ inline float row_dot4(const float* __restrict__ Wrow,
                                 const float4 hr[4], int lane) {
    const float4* w4 = (const float4*)Wrow;
    float s = 0.f;
#pragma unroll
    for (int j = 0; j < 4; ++j) {
        float4 w = w4[lane + 64 * j];
        s = fmaf(w.x, hr[j].x, s); s = fmaf(w.y, hr[j].y, s);
        s = fmaf(w.z, hr[j].z, s); s = fmaf(w.w, hr[j].w, s);
    }
#pragma unroll
    for (int off = 32; off; off >>= 1) s += __shfl_xor(s, off, 64);
    return s;
}

// ---------------- init ----------------
__global__ void init_kernel(const float* __restrict__ inp,
                            float* __restrict__ x, float* __restrict__ h,
                            float* __restrict__ c) {
    int i = threadIdx.x;  // 1024
    if (i < E_DIM) x[i] = inp[i];
    h[i] = 0.f; c[i] = 0.f;
}

// ---------------- gates matvec, optionally fused with previous-step finalize ----------------
__global__ void gatesfin_kernel(const float* __restrict__ Wih,
                                const float* __restrict__ Whh,
                                const float* __restrict__ bih,
                                const float* __restrict__ bhh,
                                const float* __restrict__ xg,
                                const float* __restrict__ h,
                                float* __restrict__ gates,
                                const float2* __restrict__ LE,
                                const float2* __restrict__ pblock,
                                const float* __restrict__ Wlin,
                                const float* __restrict__ blin,
                                const float* __restrict__ emb,
                                int* __restrict__ tok_out, int doFin) {
    const int tid = threadIdx.x, lane = tid & 63, wave = tid >> 6;  // 256 thr, 4 waves

    float4 hr[4];
    load_h4(h, hr, lane);

    __shared__ float s_wmx[4];
    __shared__ float s_M;
    __shared__ int s_nb, s_nc, s_ovf;
    __shared__ int s_blist[BL_CAP];
    __shared__ int s_clist[CAND_CAP];
    __shared__ unsigned long long s_bp[4];
    __shared__ int s_tok;

    float4 xr[2];
    if (doFin) {
        // ---- finalize of previous step, block-redundant (deterministic) ----
        float2 pb0 = pblock[tid];
        float2 pb1 = pblock[tid + 256];
        float m = fmaxf(pb0.x, pb1.x);
#pragma unroll
        for (int off = 32; off; off >>= 1) m = fmaxf(m, __shfl_xor(m, off, 64));
        if (lane == 0) s_wmx[wave] = m;
        __syncthreads();
        if (tid == 0) {
            s_M = fmaxf(fmaxf(s_wmx[0], s_wmx[1]), fmaxf(s_wmx[2], s_wmx[3]));
            s_nb = 0; s_nc = 0; s_ovf = 0;
        }
        __syncthreads();
        const float M = s_M;
        if (pb0.y >= M) { int p = atomicAdd(&s_nb, 1); if (p < BL_CAP) s_blist[p] = tid; else s_ovf = 1; }
        if (pb1.y >= M) { int p = atomicAdd(&s_nb, 1); if (p < BL_CAP) s_blist[p] = tid + 256; else s_ovf = 1; }
        __syncthreads();
        if (!s_ovf) {
            int nb = s_nb < BL_CAP ? s_nb : BL_CAP;
            for (int bi = 0; bi < nb; ++bi) {
                int r = s_blist[bi] * RPB + tid;
                if (tid < RPB && r < V_DIM) {
                    float2 le = LE[r];
                    if (le.x + le.y >= M) {
                        int p = atomicAdd(&s_nc, 1);
                        if (p < CAND_CAP) s_clist[p] = r; else s_ovf = 1;
                    }
                }
                __syncthreads();
            }
        }
        __syncthreads();
        if (tid == 0 && s_nc == 0) s_ovf = 1;   // defensive (cannot happen if bounds sound)
        __syncthreads();
        const int ovf = s_ovf;
        const int n = s_nc < CAND_CAP ? s_nc : CAND_CAP;

        unsigned long long bestp = 0ull;
        if (!ovf) {
            for (int ci = wave; ci < n; ci += 4) {
                int row = s_clist[ci];
                float s = row_dot4(Wlin + (size_t)row * H_DIM, hr, lane) + blin[row];
                unsigned long long p = packmax(s, row);
                if (p > bestp) bestp = p;
            }
        } else {  // safety net only
            for (int row = wave; row < V_DIM; row += 4) {
                float s = row_dot4(Wlin + (size_t)row * H_DIM, hr, lane) + blin[row];
                unsigned long long p = packmax(s, row);
                if (p > bestp) bestp = p;
            }
        }
        if (lane == 0) s_bp[wave] = bestp;
        __syncthreads();
        if (tid == 0) {
            unsigned long long B = s_bp[0];
            for (int w = 1; w < 4; ++w) if (s_bp[w] > B) B = s_bp[w];
            int tok = (int)(0xFFFFFFFFu - (unsigned)(B & 0xFFFFFFFFu));
            s_tok = tok;
            *tok_out = tok;
        }
        __syncthreads();
        int tokc = s_tok;
        if (tokc < 0) tokc = 0;
        if (tokc >= V_DIM) tokc = V_DIM - 1;
        const float4* e4 = (const float4*)(emb + (size_t)tokc * E_DIM);
        xr[0] = e4[lane]; xr[1] = e4[lane + 64];
    } else {
        const float4* x4 = (const float4*)xg;
        xr[0] = x4[lane]; xr[1] = x4[lane + 64];
    }

    // ---- gates matvec: 4096 rows over 1024 waves ----
    for (int row = blockIdx.x * 4 + wave; row < 4 * H_DIM; row += NB_GATES * 4) {
        const float4* wi = (const float4*)(Wih + (size_t)row * E_DIM);
        const float4* wh = (const float4*)(Whh + (size_t)row * H_DIM);
        float s = 0.f;
#pragma unroll
        for (int j = 0; j < 2; ++j) {
            float4 w = wi[lane + j * 64];
            s = fmaf(w.x, xr[j].x, s); s = fmaf(w.y, xr[j].y, s);
            s = fmaf(w.z, xr[j].z, s); s = fmaf(w.w, xr[j].w, s);
        }
#pragma unroll
        for (int j = 0; j < 4; ++j) {
            float4 w = wh[lane + j * 64];
            s = fmaf(w.x, hr[j].x, s); s = fmaf(w.y, hr[j].y, s);
            s = fmaf(w.z, hr[j].z, s); s = fmaf(w.w, hr[j].w, s);
        }
#pragma unroll
        for (int off = 32; off; off >>= 1) s += __shfl_xor(s, off, 64);
        if (lane == 0) gates[row] = s + bih[row] + bhh[row];
    }
}

// ---------------- standalone LSTM cell (step 0 / fallback) ----------------
__global__ void cell_kernel(const float* __restrict__ gates,
                            float* __restrict__ c, float* __restrict__ h,
                            float* __restrict__ hn) {
    int j = threadIdx.x;  // 1024, 1 block
    float iv = sigm(gates[j]);
    float fv = sigm(gates[j + H_DIM]);
    float gv = tanhf(gates[j + 2 * H_DIM]);
    float ov = sigm(gates[j + 3 * H_DIM]);
    float cv = fv * c[j] + iv * gv;
    c[j] = cv;
    float hv = ov * tanhf(cv);
    h[j] = hv;

    float sq = hv * hv;
#pragma unroll
    for (int off = 32; off; off >>= 1) sq += __shfl_xor(sq, off, 64);
    __shared__ float ws[16];
    int lane = j & 63, wv = j >> 6;
    if (lane == 0) ws[wv] = sq;
    __syncthreads();
    if (j == 0) {
        float t = 0.f;
        for (int w = 0; w < 16; ++w) t += ws[w];
        *hn = sqrtf(t);
    }
}

// ---------------- step-0: fp32 logits + int8 convert (scale, residual norm) ----------------
__global__ void logits_f32_kernel(const float* __restrict__ Wlin,
                                  const float* __restrict__ blin,
                                  const float* __restrict__ h,
                                  uint4* __restrict__ WbI,
                                  float4* __restrict__ SNB, int doConv,
                                  unsigned long long* __restrict__ partials) {
    const int tid = threadIdx.x, lane = tid & 63, wave = tid >> 6;
    const int gw = blockIdx.x * 4 + wave;

    float4 hr[4];
    load_h4(h, hr, lane);

    float best = -INFINITY;
    int bidx = 0x7fffffff;
    for (int row = gw; row < V_DIM; row += NB_F32 * 4) {
        const float4* w4 = (const float4*)(Wlin + (size_t)row * H_DIM);
        float4 A[4];
#pragma unroll
        for (int j = 0; j < 4; ++j) A[j] = w4[lane + 64 * j];

        float s = 0.f, mx = 0.f;
#pragma unroll
        for (int j = 0; j < 4; ++j) {
            s = fmaf(A[j].x, hr[j].x, s); s = fmaf(A[j].y, hr[j].y, s);
            s = fmaf(A[j].z, hr[j].z, s); s = fmaf(A[j].w, hr[j].w, s);
            mx = fmaxf(mx, fmaxf(fmaxf(fabsf(A[j].x), fabsf(A[j].y)),
                                 fmaxf(fabsf(A[j].z), fabsf(A[j].w))));
        }
#pragma unroll
        for (int off = 32; off; off >>= 1) {
            s += __shfl_xor(s, off, 64);
            mx = fmaxf(mx, __shfl_xor(mx, off, 64));
        }

        if (doConv) {
            float scale = mx * (1.0f / 127.0f);
            float inv = (mx > 0.f) ? (127.0f / mx) : 0.f;
            float d2 = 0.f;
            unsigned pw[4];
#pragma unroll
            for (int j = 0; j < 4; ++j) {
                float q0 = fminf(fmaxf(rintf(A[j].x * inv), -127.f), 127.f);
                float q1 = fminf(fmaxf(rintf(A[j].y * inv), -127.f), 127.f);
                float q2 = fminf(fmaxf(rintf(A[j].z * inv), -127.f), 127.f);
                float q3 = fminf(fmaxf(rintf(A[j].w * inv), -127.f), 127.f);
                float r0 = A[j].x - q0 * scale;
                float r1 = A[j].y - q1 * scale;
                float r2 = A[j].z - q2 * scale;
                float r3 = A[j].w - q3 * scale;
                d2 = fmaf(r0, r0, d2); d2 = fmaf(r1, r1, d2);
                d2 = fmaf(r2, r2, d2); d2 = fmaf(r3, r3, d2);
                pw[j] = ((unsigned)(int)q0 & 0xFFu) | (((unsigned)(int)q1 & 0xFFu) << 8) |
                        (((unsigned)(int)q2 & 0xFFu) << 16) | (((unsigned)(int)q3 & 0xFFu) << 24);
            }
#pragma unroll
            for (int off = 32; off; off >>= 1) d2 += __shfl_xor(d2, off, 64);
            WbI[(size_t)row * 64 + lane] = make_uint4(pw[0], pw[1], pw[2], pw[3]);
            if (lane == 0)
                SNB[row] = make_float4(scale, sqrtf(d2) + 3e-3f * mx, blin[row], 0.f);
        }
        s += blin[row];
        if (s > best) { best = s; bidx = row; }
    }

    __shared__ float bv[4];
    __shared__ int bi[4];
    if (lane == 0) { bv[wave] = best; bi[wave] = bidx; }
    __syncthreads();
    if (tid == 0) {
        float B = bv[0]; int I = bi[0];
        for (int w = 1; w < 4; ++w)
            if (bv[w] > B || (bv[w] == B && bi[w] < I)) { B = bv[w]; I = bi[w]; }
        partials[blockIdx.x] = packmax(B, I);
    }
}

__global__ void finalize_f32_kernel(const unsigned long long* __restrict__ partials,
                                    const float* __restrict__ emb,
                                    float* __restrict__ x, int* __restrict__ tok_out) {
    const int lane = threadIdx.x & 63, wave = threadIdx.x >> 6;
    unsigned long long best = 0ull;
    for (int i = threadIdx.x; i < NB_F32; i += 256) {
        unsigned long long p = partials[i];
        if (p > best) best = p;
    }
#pragma unroll
    for (int off = 32; off; off >>= 1) {
        unsigned long long o = __shfl_xor(best, off, 64);
        if (o > best) best = o;
    }
    __shared__ unsigned long long sb[4];
    __shared__ int stok;
    if (lane == 0) sb[wave] = best;
    __syncthreads();
    if (threadIdx.x == 0) {
        unsigned long long B = sb[0];
        for (int w = 1; w < 4; ++w) if (sb[w] > B) B = sb[w];
        int tok = (int)(0xFFFFFFFFu - (unsigned)(B & 0xFFFFFFFFu));
        *tok_out = tok;
        stok = tok;
    }
    __syncthreads();
    int tok = stok;
    if (tok < 0) tok = 0;
    if (tok >= V_DIM) tok = V_DIM - 1;
    const float4* e4 = (const float4*)(emb + (size_t)tok * E_DIM);
    float4* x4 = (float4*)x;
    if (threadIdx.x < E_DIM / 4) x4[threadIdx.x] = e4[threadIdx.x];
}

// ------- int8 logits scan with cooperative (LDS) fused LSTM cell -------
// 512 threads = 8 waves; waves 0-3 compute h,c into LDS; all waves consume.
__global__ void logits_i8_kernel(const uint4* __restrict__ WbI,
                                 const float4* __restrict__ SNB,
                                 const float* __restrict__ gates,
                                 const float* __restrict__ cin,
                                 float* __restrict__ cout,
                                 float* __restrict__ hout,
                                 float2* __restrict__ LE,
                                 float2* __restrict__ pblock) {
    const int tid = threadIdx.x, lane = tid & 63, wave = tid >> 6;  // 8 waves
    const int wid = blockIdx.x * 8 + wave;
    const int r0 = wid * RPW;
    int nrows = V_DIM - r0;
    nrows = nrows < 0 ? 0 : (nrows > RPW ? RPW : nrows);

    // issue first PF row loads before the cell (latency hides under transcendentals)
    const uint4* rb = WbI + (size_t)r0 * 64 + lane;
    uint4 wq[RPW];
#pragma unroll
    for (int k = 0; k < PF; ++k)
        if (k < nrows) wq[k] = rb[(size_t)k * 64];

    __shared__ float h_lds[H_DIM];
    __shared__ float cpart[4];

    if (wave < 4) {
        const int idx4 = wave * 64 + lane;  // float4 index 0..255
        const float4* g4i = (const float4*)gates;
        const float4* g4f = (const float4*)(gates + H_DIM);
        const float4* g4g = (const float4*)(gates + 2 * H_DIM);
        const float4* g4o = (const float4*)(gates + 3 * H_DIM);
        const float4* c4  = (const float4*)cin;
        float4 gi = g4i[idx4], gf = g4f[idx4], gg = g4g[idx4], go = g4o[idx4], cc = c4[idx4];
        float4 hv, cv;
        cv.x = sigm(gf.x) * cc.x + sigm(gi.x) * tanhf(gg.x);
        cv.y = sigm(gf.y) * cc.y + sigm(gi.y) * tanhf(gg.y);
        cv.z = sigm(gf.z) * cc.z + sigm(gi.z) * tanhf(gg.z);
        cv.w = sigm(gf.w) * cc.w + sigm(gi.w) * tanhf(gg.w);
        hv.x = sigm(go.x) * tanhf(cv.x);
        hv.y = sigm(go.y) * tanhf(cv.y);
        hv.z = sigm(go.z) * tanhf(cv.z);
        hv.w = sigm(go.w) * tanhf(cv.w);
        ((float4*)h_lds)[idx4] = hv;
        if (blockIdx.x == 0) {
            ((float4*)hout)[idx4] = hv;
            ((float4*)cout)[idx4] = cv;
        }
        float sq = fmaf(hv.x, hv.x, fmaf(hv.y, hv.y, fmaf(hv.z, hv.z, hv.w * hv.w)));
#pragma unroll
        for (int off = 32; off; off >>= 1) sq += __shfl_xor(sq, off, 64);
        if (lane == 0) cpart[wave] = sq;
    }
    __syncthreads();
    const float K = sqrtf(cpart[0] + cpart[1] + cpart[2] + cpart[3]);  // ||h||_2

    float4 hr[4];
#pragma unroll
    for (int j = 0; j < 4; ++j) hr[j] = ((const float4*)h_lds)[lane + 64 * j];

    float maxl = -INFINITY, maxu = -INFINITY;
#pragma unroll
    for (int k = 0; k < RPW; ++k) {
        if (k >= nrows) break;
        if (k + PF < RPW && k + PF < nrows) wq[k + PF] = rb[(size_t)(k + PF) * 64];
        uint4 c = wq[k];
        float s = 0.f;
        {
            int v = (int)c.x;
            s = fmaf((float)((v << 24) >> 24), hr[0].x, s);
            s = fmaf((float)((v << 16) >> 24), hr[0].y, s);
            s = fmaf((float)((v << 8) >> 24),  hr[0].z, s);
            s = fmaf((float)(v >> 24),         hr[0].w, s);
        }
        {
            int v = (int)c.y;
            s = fmaf((float)((v << 24) >> 24), hr[1].x, s);
            s = fmaf((float)((v << 16) >> 24), hr[1].y, s);
            s = fmaf((float)((v << 8) >> 24),  hr[1].z, s);
            s = fmaf((float)(v >> 24),         hr[1].w, s);
        }
        {
            int v = (int)c.z;
            s = fmaf((float)((v << 24) >> 24), hr[2].x, s);
            s = fmaf((float)((v << 16) >> 24), hr[2].y, s);
            s = fmaf((float)((v << 8) >> 24),  hr[2].z, s);
            s = fmaf((float)(v >> 24),         hr[2].w, s);
        }
        {
            int v = (int)c.w;
            s = fmaf((float)((v << 24) >> 24), hr[3].x, s);
            s = fmaf((float)((v << 16) >> 24), hr[3].y, s);
            s = fmaf((float)((v << 8) >> 24),  hr[3].z, s);
            s = fmaf((float)(v >> 24),         hr[3].w, s);
        }
#pragma unroll
        for (int off = 32; off; off >>= 1) s += __shfl_xor(s, off, 64);
        int r = r0 + k;
        float4 snb = SNB[r];
        float L = fmaf(snb.x, s, snb.z);
        float e = fmaf(snb.y, K, 1e-6f);
        if (lane == 0) LE[r] = make_float2(L, e);
        maxl = fmaxf(maxl, L - e);
        maxu = fmaxf(maxu, L + e);
    }

    __shared__ float wl[8], wu[8];
    if (lane == 0) { wl[wave] = maxl; wu[wave] = maxu; }
    __syncthreads();
    if (tid == 0) {
        float lo = wl[0], up = wu[0];
        for (int w = 1; w < 8; ++w) { lo = fmaxf(lo, wl[w]); up = fmaxf(up, wu[w]); }
        pblock[blockIdx.x] = make_float2(lo, up);
    }
}

// ------- standalone tail finalize (last step only) -------
__global__ void finalize_tail_kernel(const float2* __restrict__ LE,
                                     const float2* __restrict__ pblock,
                                     const float* __restrict__ Wlin,
                                     const float* __restrict__ blin,
                                     const float* __restrict__ h,
                                     const float* __restrict__ emb,
                                     float* __restrict__ x, int* __restrict__ tok_out) {
    const int tid = threadIdx.x;              // 1024 threads
    const int lane = tid & 63, wv = tid >> 6; // 16 waves

    __shared__ float wmx[16];
    __shared__ float sM;
    __shared__ int snb, sncand, sovf;
    __shared__ int blist[BL_CAP];
    __shared__ int clist[CAND_CAP];

    float2 pb = make_float2(-INFINITY, -INFINITY);
    if (tid < NB_LOG) pb = pblock[tid];
    float m = pb.x;
#pragma unroll
    for (int off = 32; off; off >>= 1) m = fmaxf(m, __shfl_xor(m, off, 64));
    if (lane == 0) wmx[wv] = m;
    __syncthreads();
    if (tid == 0) {
        float M = wmx[0];
        for (int w = 1; w < 16; ++w) M = fmaxf(M, wmx[w]);
        sM = M; snb = 0; sncand = 0; sovf = 0;
    }
    __syncthreads();
    const float M = sM;

    if (tid < NB_LOG && pb.y >= M) {
        int p = atomicAdd(&snb, 1);
        if (p < BL_CAP) blist[p] = tid; else sovf = 1;
    }
    __syncthreads();
    if (!sovf) {
        int nb = snb < BL_CAP ? snb : BL_CAP;
        for (int bi = 0; bi < nb; ++bi) {
            int r = blist[bi] * RPB + tid;
            if (tid < RPB && r < V_DIM) {
                float2 le = LE[r];
                if (le.x + le.y >= M) {
                    int p = atomicAdd(&sncand, 1);
                    if (p < CAND_CAP) clist[p] = r; else sovf = 1;
                }
            }
            __syncthreads();
        }
    }
    __syncthreads();
    if (tid == 0 && sncand == 0) sovf = 1;
    __syncthreads();
    const int ovf = sovf;
    const int n = sncand < CAND_CAP ? sncand : CAND_CAP;

    float4 hr[4];
    load_h4(h, hr, lane);
    unsigned long long bestp = 0ull;
    if (!ovf) {
        for (int ci = wv; ci < n; ci += 16) {
            int row = clist[ci];
            float s = row_dot4(Wlin + (size_t)row * H_DIM, hr, lane) + blin[row];
            unsigned long long p = packmax(s, row);
            if (p > bestp) bestp = p;
        }
    } else {
        for (int row = wv; row < V_DIM; row += 16) {
            float s = row_dot4(Wlin + (size_t)row * H_DIM, hr, lane) + blin[row];
            unsigned long long p = packmax(s, row);
            if (p > bestp) bestp = p;
        }
    }
    __shared__ unsigned long long sbp[16];
    __shared__ int stok;
    if (lane == 0) sbp[wv] = bestp;
    __syncthreads();
    if (tid == 0) {
        unsigned long long B = sbp[0];
        for (int w = 1; w < 16; ++w) if (sbp[w] > B) B = sbp[w];
        int tok = (int)(0xFFFFFFFFu - (unsigned)(B & 0xFFFFFFFFu));
        stok = tok;
        *tok_out = tok;
    }
    __syncthreads();
    int tok = stok;
    if (tok < 0) tok = 0;
    if (tok >= V_DIM) tok = V_DIM - 1;
    const float4* e4 = (const float4*)(emb + (size_t)tok * E_DIM);
    float4* xo = (float4*)x;
    if (tid < E_DIM / 4) xo[tid] = e4[tid];
}

extern "C" void kernel_launch(void* const* d_in, const int* in_sizes, int n_in,
                              void* d_out, int out_size, void* d_ws, size_t ws_size,
                              hipStream_t stream) {
    const float* inp  = (const float*)d_in[0];
    const float* Wih  = (const float*)d_in[1];
    const float* Whh  = (const float*)d_in[2];
    const float* bih  = (const float*)d_in[3];
    const float* bhh  = (const float*)d_in[4];
    const float* emb  = (const float*)d_in[5];
    const float* Wlin = (const float*)d_in[6];
    const float* blin = (const float*)d_in[7];
    int* toks = (int*)d_out;

    char* ws = (char*)d_ws;
    float* x     = (float*)(ws + OFF_X);
    float* h     = (float*)(ws + OFF_H);
    float* c0b   = (float*)(ws + OFF_C);
    float* c1b   = (float*)(ws + OFF_C2);
    float* gates = (float*)(ws + OFF_GATES);
    float* hn    = (float*)(ws + OFF_HN);
    unsigned long long* partials = (unsigned long long*)(ws + OFF_PART);
    float2* pblock = (float2*)(ws + OFF_PBLOCK);
    float4* SNB  = (float4*)(ws + OFF_SNB);
    float2* LE   = (float2*)(ws + OFF_LE);
    uint4* WbI   = (uint4*)(ws + OFF_WBI);

    const int useI8 = (ws_size >= WS_NEEDED) ? 1 : 0;

    init_kernel<<<1, 1024, 0, stream>>>(inp, x, h, c0b);

    if (!useI8) {
        for (int step = 0; step < NSTEPS; ++step) {
            gatesfin_kernel<<<NB_GATES, 256, 0, stream>>>(
                Wih, Whh, bih, bhh, x, h, gates, LE, pblock, Wlin, blin, emb,
                (int*)nullptr, 0);
            cell_kernel<<<1, 1024, 0, stream>>>(gates, c0b, h, hn);
            logits_f32_kernel<<<NB_F32, 256, 0, stream>>>(
                Wlin, blin, h, WbI, SNB, 0, partials);
            finalize_f32_kernel<<<1, 256, 0, stream>>>(partials, emb, x, toks + step);
        }
        return;
    }

    // ---- step 0: fp32 exact scan + int8 conversion ----
    gatesfin_kernel<<<NB_GATES, 256, 0, stream>>>(
        Wih, Whh, bih, bhh, x, h, gates, LE, pblock, Wlin, blin, emb,
        (int*)nullptr, 0);
    cell_kernel<<<1, 1024, 0, stream>>>(gates, c0b, h, hn);
    logits_f32_kernel<<<NB_F32, 256, 0, stream>>>(
        Wlin, blin, h, WbI, SNB, 1, partials);
    finalize_f32_kernel<<<1, 256, 0, stream>>>(partials, emb, x, toks + 0);

    // ---- steps 1..18: 2 kernels per step ----
    for (int t = 1; t < NSTEPS; ++t) {
        gatesfin_kernel<<<NB_GATES, 256, 0, stream>>>(
            Wih, Whh, bih, bhh, x, h, gates, LE, pblock, Wlin, blin, emb,
            (t >= 2) ? (toks + t - 1) : (int*)nullptr, (t >= 2) ? 1 : 0);
        float* cin  = (t & 1) ? c0b : c1b;
        float* cout = (t & 1) ? c1b : c0b;
        logits_i8_kernel<<<NB_LOG, 512, 0, stream>>>(
            WbI, SNB, gates, cin, cout, h, LE, pblock);
    }
    // tail: finalize step 18
    finalize_tail_kernel<<<1, 1024, 0, stream>>>(LE, pblock, Wlin, blin, h, emb,
                                                 x, toks + NSTEPS - 1);
}

// Round 8
// 435.312 us; speedup vs baseline: 1.6956x; 1.6956x over previous
//
#include <hip/hip_runtime.h>
#include <hip/hip_bf16.h>
#include <math.h>

#define E_DIM 512
#define H_DIM 1024
#define V_DIM 50257
#define NSTEPS 19
#define NB_F32 1024      // fp32 logits blocks (4 waves each)
#define NB_LOG 484       // int8 scan blocks (8 waves each) -> 3872 waves
#define RPW 13           // rows per wave (3872*13 = 50336 >= V)
#define RPB 104          // rows per scan block (8*13)
#define VPAD 50336       // padded row count (3872*13)
#define NB_GATES 256
#define BL_CAP 192
#define CAND_CAP 1024
#define PF 4             // row prefetch depth (all-static indices)

// ---- workspace layout (bytes), NO overlaps, 16B-aligned ----
#define OFF_X      0          // 512 f
#define OFF_H      4096       // 1024 f
#define OFF_C      8192       // 1024 f (ping)
#define OFF_C2     12288      // 1024 f (pong)
#define OFF_GATES  16384      // 4096 f (ends 32768)
#define OFF_HN     32768      // 1 f
#define OFF_PART   33024      // 1024 u64 (ends 41216)
#define OFF_PBLOCK 41216      // 484 float2 (ends 45088)
#define OFF_SNB    49152      // VPAD float4 {scale, nrm, bias, 0} (ends 854528)
#define OFF_LE     854528     // VPAD float2 {L, e} (ends 1257216)
#define OFF_WBI    1257216    // int8 W_lin, VPAD*1024 B (ends 52801280)
#define WS_NEEDED  52801280ull

__device__ inline unsigned fmap(float f) {
    unsigned u = __float_as_uint(f);
    return (u & 0x80000000u) ? ~u : (u | 0x80000000u);
}
__device__ inline unsigned long long packmax(float s, int row) {
    return ((unsigned long long)fmap(s) << 32) | (unsigned)(0xFFFFFFFFu - (unsigned)row);
}
__device__ inline float sigm(float v) { return 1.0f / (1.0f + expf(-v)); }

// h fragment layout "hr4": hr[j] = h4[lane + 64j] (covers all 1024)
__device__ inline void load_h4(const float* __restrict__ h, float4 hr[4], int lane) {
    const float4* h4 = (const float4*)h;
#pragma unroll
    for (int j = 0; j < 4; ++j) hr[j] = h4[lane + 64 * j];
}
// exact fp32 wave-collective row dot (hr4 layout, broadcast result)
__device__ inline float row_dot4(const float* __restrict__ Wrow,
                                 const float4 hr[4], int lane) {
    const float4* w4 = (const float4*)Wrow;
    float s = 0.f;
#pragma unroll
    for (int j = 0; j < 4; ++j) {
        float4 w = w4[lane + 64 * j];
        s = fmaf(w.x, hr[j].x, s); s = fmaf(w.y, hr[j].y, s);
        s = fmaf(w.z, hr[j].z, s); s = fmaf(w.w, hr[j].w, s);
    }
#pragma unroll
    for (int off = 32; off; off >>= 1) s += __shfl_xor(s, off, 64);
    return s;
}

// ---------------- init: states + pad SNB entries ----------------
__global__ void init_kernel(const float* __restrict__ inp,
                            float* __restrict__ x, float* __restrict__ h,
                            float* __restrict__ c, float4* __restrict__ SNB) {
    int i = threadIdx.x;  // 1024
    if (i < E_DIM) x[i] = inp[i];
    h[i] = 0.f; c[i] = 0.f;
    if (i < VPAD - V_DIM) SNB[V_DIM + i] = make_float4(0.f, 0.f, -1e30f, 0.f);
}

// ---------------- gates matvec, optionally fused with previous-step finalize ----------------
__global__ void gatesfin_kernel(const float* __restrict__ Wih,
                                const float* __restrict__ Whh,
                                const float* __restrict__ bih,
                                const float* __restrict__ bhh,
                                const float* __restrict__ xg,
                                const float* __restrict__ h,
                                float* __restrict__ gates,
                                const float2* __restrict__ LE,
                                const float2* __restrict__ pblock,
                                const float* __restrict__ Wlin,
                                const float* __restrict__ blin,
                                const float* __restrict__ emb,
                                int* __restrict__ tok_out, int doFin) {
    const int tid = threadIdx.x, lane = tid & 63, wave = tid >> 6;  // 256 thr, 4 waves

    float4 hr[4];
    load_h4(h, hr, lane);

    __shared__ float s_wmx[4];
    __shared__ float s_M;
    __shared__ int s_nb, s_nc, s_ovf;
    __shared__ int s_blist[BL_CAP];
    __shared__ int s_clist[CAND_CAP];
    __shared__ unsigned long long s_bp[4];
    __shared__ int s_tok;

    float4 xr[2];
    if (doFin) {
        // ---- finalize of previous step, block-redundant (deterministic) ----
        float2 pb0 = pblock[tid];
        float2 pb1 = (tid + 256 < NB_LOG) ? pblock[tid + 256]
                                          : make_float2(-INFINITY, -INFINITY);
        float m = fmaxf(pb0.x, pb1.x);
#pragma unroll
        for (int off = 32; off; off >>= 1) m = fmaxf(m, __shfl_xor(m, off, 64));
        if (lane == 0) s_wmx[wave] = m;
        __syncthreads();
        if (tid == 0) {
            s_M = fmaxf(fmaxf(s_wmx[0], s_wmx[1]), fmaxf(s_wmx[2], s_wmx[3]));
            s_nb = 0; s_nc = 0; s_ovf = 0;
        }
        __syncthreads();
        const float M = s_M;
        if (pb0.y >= M) { int p = atomicAdd(&s_nb, 1); if (p < BL_CAP) s_blist[p] = tid; else s_ovf = 1; }
        if (pb1.y >= M) { int p = atomicAdd(&s_nb, 1); if (p < BL_CAP) s_blist[p] = tid + 256; else s_ovf = 1; }
        __syncthreads();
        if (!s_ovf) {
            // flattened, barrier-free candidate-row scan (pad rows have L=-1e30)
            int nb = s_nb < BL_CAP ? s_nb : BL_CAP;
            for (int ii = tid; ii < nb * RPB; ii += 256) {
                int bi = ii / RPB, off = ii - bi * RPB;
                int r = s_blist[bi] * RPB + off;
                float2 le = LE[r];
                if (le.x + le.y >= M) {
                    int p = atomicAdd(&s_nc, 1);
                    if (p < CAND_CAP) s_clist[p] = r; else s_ovf = 1;
                }
            }
        }
        __syncthreads();
        if (tid == 0 && s_nc == 0) s_ovf = 1;   // defensive
        __syncthreads();
        const int ovf = s_ovf;
        const int n = s_nc < CAND_CAP ? s_nc : CAND_CAP;

        unsigned long long bestp = 0ull;
        if (!ovf) {
            for (int ci = wave; ci < n; ci += 4) {
                int row = s_clist[ci];
                float s = row_dot4(Wlin + (size_t)row * H_DIM, hr, lane) + blin[row];
                unsigned long long p = packmax(s, row);
                if (p > bestp) bestp = p;
            }
        } else {  // safety net only
            for (int row = wave; row < V_DIM; row += 4) {
                float s = row_dot4(Wlin + (size_t)row * H_DIM, hr, lane) + blin[row];
                unsigned long long p = packmax(s, row);
                if (p > bestp) bestp = p;
            }
        }
        if (lane == 0) s_bp[wave] = bestp;
        __syncthreads();
        if (tid == 0) {
            unsigned long long B = s_bp[0];
            for (int w = 1; w < 4; ++w) if (s_bp[w] > B) B = s_bp[w];
            int tok = (int)(0xFFFFFFFFu - (unsigned)(B & 0xFFFFFFFFu));
            s_tok = tok;
            *tok_out = tok;
        }
        __syncthreads();
        int tokc = s_tok;
        if (tokc < 0) tokc = 0;
        if (tokc >= V_DIM) tokc = V_DIM - 1;
        const float4* e4 = (const float4*)(emb + (size_t)tokc * E_DIM);
        xr[0] = e4[lane]; xr[1] = e4[lane + 64];
    } else {
        const float4* x4 = (const float4*)xg;
        xr[0] = x4[lane]; xr[1] = x4[lane + 64];
    }

    // ---- gates matvec: 4096 rows over 1024 waves ----
    for (int row = blockIdx.x * 4 + wave; row < 4 * H_DIM; row += NB_GATES * 4) {
        const float4* wi = (const float4*)(Wih + (size_t)row * E_DIM);
        const float4* wh = (const float4*)(Whh + (size_t)row * H_DIM);
        float s = 0.f;
#pragma unroll
        for (int j = 0; j < 2; ++j) {
            float4 w = wi[lane + j * 64];
            s = fmaf(w.x, xr[j].x, s); s = fmaf(w.y, xr[j].y, s);
            s = fmaf(w.z, xr[j].z, s); s = fmaf(w.w, xr[j].w, s);
        }
#pragma unroll
        for (int j = 0; j < 4; ++j) {
            float4 w = wh[lane + j * 64];
            s = fmaf(w.x, hr[j].x, s); s = fmaf(w.y, hr[j].y, s);
            s = fmaf(w.z, hr[j].z, s); s = fmaf(w.w, hr[j].w, s);
        }
#pragma unroll
        for (int off = 32; off; off >>= 1) s += __shfl_xor(s, off, 64);
        if (lane == 0) gates[row] = s + bih[row] + bhh[row];
    }
}

// ---------------- standalone LSTM cell (step 0 / fallback) ----------------
__global__ void cell_kernel(const float* __restrict__ gates,
                            float* __restrict__ c, float* __restrict__ h,
                            float* __restrict__ hn) {
    int j = threadIdx.x;  // 1024, 1 block
    float iv = sigm(gates[j]);
    float fv = sigm(gates[j + H_DIM]);
    float gv = tanhf(gates[j + 2 * H_DIM]);
    float ov = sigm(gates[j + 3 * H_DIM]);
    float cv = fv * c[j] + iv * gv;
    c[j] = cv;
    float hv = ov * tanhf(cv);
    h[j] = hv;

    float sq = hv * hv;
#pragma unroll
    for (int off = 32; off; off >>= 1) sq += __shfl_xor(sq, off, 64);
    __shared__ float ws[16];
    int lane = j & 63, wv = j >> 6;
    if (lane == 0) ws[wv] = sq;
    __syncthreads();
    if (j == 0) {
        float t = 0.f;
        for (int w = 0; w < 16; ++w) t += ws[w];
        *hn = sqrtf(t);
    }
}

// ---------------- step-0: fp32 logits + int8 convert (scale, residual norm) ----------------
__global__ void logits_f32_kernel(const float* __restrict__ Wlin,
                                  const float* __restrict__ blin,
                                  const float* __restrict__ h,
                                  uint4* __restrict__ WbI,
                                  float4* __restrict__ SNB, int doConv,
                                  unsigned long long* __restrict__ partials) {
    const int tid = threadIdx.x, lane = tid & 63, wave = tid >> 6;
    const int gw = blockIdx.x * 4 + wave;

    float4 hr[4];
    load_h4(h, hr, lane);

    float best = -INFINITY;
    int bidx = 0x7fffffff;
    for (int row = gw; row < V_DIM; row += NB_F32 * 4) {
        const float4* w4 = (const float4*)(Wlin + (size_t)row * H_DIM);
        float4 A[4];
#pragma unroll
        for (int j = 0; j < 4; ++j) A[j] = w4[lane + 64 * j];

        float s = 0.f, mx = 0.f;
#pragma unroll
        for (int j = 0; j < 4; ++j) {
            s = fmaf(A[j].x, hr[j].x, s); s = fmaf(A[j].y, hr[j].y, s);
            s = fmaf(A[j].z, hr[j].z, s); s = fmaf(A[j].w, hr[j].w, s);
            mx = fmaxf(mx, fmaxf(fmaxf(fabsf(A[j].x), fabsf(A[j].y)),
                                 fmaxf(fabsf(A[j].z), fabsf(A[j].w))));
        }
#pragma unroll
        for (int off = 32; off; off >>= 1) {
            s += __shfl_xor(s, off, 64);
            mx = fmaxf(mx, __shfl_xor(mx, off, 64));
        }

        if (doConv) {
            float scale = mx * (1.0f / 127.0f);
            float inv = (mx > 0.f) ? (127.0f / mx) : 0.f;
            float d2 = 0.f;
            unsigned pw[4];
#pragma unroll
            for (int j = 0; j < 4; ++j) {
                float q0 = fminf(fmaxf(rintf(A[j].x * inv), -127.f), 127.f);
                float q1 = fminf(fmaxf(rintf(A[j].y * inv), -127.f), 127.f);
                float q2 = fminf(fmaxf(rintf(A[j].z * inv), -127.f), 127.f);
                float q3 = fminf(fmaxf(rintf(A[j].w * inv), -127.f), 127.f);
                float r0 = A[j].x - q0 * scale;
                float r1 = A[j].y - q1 * scale;
                float r2 = A[j].z - q2 * scale;
                float r3 = A[j].w - q3 * scale;
                d2 = fmaf(r0, r0, d2); d2 = fmaf(r1, r1, d2);
                d2 = fmaf(r2, r2, d2); d2 = fmaf(r3, r3, d2);
                pw[j] = ((unsigned)(int)q0 & 0xFFu) | (((unsigned)(int)q1 & 0xFFu) << 8) |
                        (((unsigned)(int)q2 & 0xFFu) << 16) | (((unsigned)(int)q3 & 0xFFu) << 24);
            }
#pragma unroll
            for (int off = 32; off; off >>= 1) d2 += __shfl_xor(d2, off, 64);
            WbI[(size_t)row * 64 + lane] = make_uint4(pw[0], pw[1], pw[2], pw[3]);
            if (lane == 0)
                SNB[row] = make_float4(scale, sqrtf(d2) + 3e-3f * mx, blin[row], 0.f);
        }
        s += blin[row];
        if (s > best) { best = s; bidx = row; }
    }

    __shared__ float bv[4];
    __shared__ int bi[4];
    if (lane == 0) { bv[wave] = best; bi[wave] = bidx; }
    __syncthreads();
    if (tid == 0) {
        float B = bv[0]; int I = bi[0];
        for (int w = 1; w < 4; ++w)
            if (bv[w] > B || (bv[w] == B && bi[w] < I)) { B = bv[w]; I = bi[w]; }
        partials[blockIdx.x] = packmax(B, I);
    }
}

__global__ void finalize_f32_kernel(const unsigned long long* __restrict__ partials,
                                    const float* __restrict__ emb,
                                    float* __restrict__ x, int* __restrict__ tok_out) {
    const int lane = threadIdx.x & 63, wave = threadIdx.x >> 6;
    unsigned long long best = 0ull;
    for (int i = threadIdx.x; i < NB_F32; i += 256) {
        unsigned long long p = partials[i];
        if (p > best) best = p;
    }
#pragma unroll
    for (int off = 32; off; off >>= 1) {
        unsigned long long o = __shfl_xor(best, off, 64);
        if (o > best) best = o;
    }
    __shared__ unsigned long long sb[4];
    __shared__ int stok;
    if (lane == 0) sb[wave] = best;
    __syncthreads();
    if (threadIdx.x == 0) {
        unsigned long long B = sb[0];
        for (int w = 1; w < 4; ++w) if (sb[w] > B) B = sb[w];
        int tok = (int)(0xFFFFFFFFu - (unsigned)(B & 0xFFFFFFFFu));
        *tok_out = tok;
        stok = tok;
    }
    __syncthreads();
    int tok = stok;
    if (tok < 0) tok = 0;
    if (tok >= V_DIM) tok = V_DIM - 1;
    const float4* e4 = (const float4*)(emb + (size_t)tok * E_DIM);
    float4* x4 = (float4*)x;
    if (threadIdx.x < E_DIM / 4) x4[threadIdx.x] = e4[threadIdx.x];
}

// ------- int8 scan with cooperative (LDS) fused LSTM cell, padded domain -------
// 512 threads = 8 waves; waves 0-3 compute h,c into LDS; all waves consume.
// Every wave does exactly RPW rows (pad rows carry bias=-1e30, never candidates).
__global__ void logits_i8_kernel(const uint4* __restrict__ WbI,
                                 const float4* __restrict__ SNB,
                                 const float* __restrict__ gates,
                                 const float* __restrict__ cin,
                                 float* __restrict__ cout,
                                 float* __restrict__ hout,
                                 float2* __restrict__ LE,
                                 float2* __restrict__ pblock) {
    const int tid = threadIdx.x, lane = tid & 63, wave = tid >> 6;  // 8 waves
    const int wid = blockIdx.x * 8 + wave;
    const int r0 = wid * RPW;

    // all-static prefetch: constant trip counts, no breaks -> stays in VGPRs
    const uint4* rb = WbI + (size_t)r0 * 64 + lane;
    uint4 wq[RPW];
#pragma unroll
    for (int k = 0; k < PF; ++k) wq[k] = rb[(size_t)k * 64];

    __shared__ float h_lds[H_DIM];
    __shared__ float cpart[4];

    if (wave < 4) {
        const int idx4 = wave * 64 + lane;  // float4 index 0..255
        const float4* g4i = (const float4*)gates;
        const float4* g4f = (const float4*)(gates + H_DIM);
        const float4* g4g = (const float4*)(gates + 2 * H_DIM);
        const float4* g4o = (const float4*)(gates + 3 * H_DIM);
        const float4* c4  = (const float4*)cin;
        float4 gi = g4i[idx4], gf = g4f[idx4], gg = g4g[idx4], go = g4o[idx4], cc = c4[idx4];
        float4 hv, cv;
        cv.x = sigm(gf.x) * cc.x + sigm(gi.x) * tanhf(gg.x);
        cv.y = sigm(gf.y) * cc.y + sigm(gi.y) * tanhf(gg.y);
        cv.z = sigm(gf.z) * cc.z + sigm(gi.z) * tanhf(gg.z);
        cv.w = sigm(gf.w) * cc.w + sigm(gi.w) * tanhf(gg.w);
        hv.x = sigm(go.x) * tanhf(cv.x);
        hv.y = sigm(go.y) * tanhf(cv.y);
        hv.z = sigm(go.z) * tanhf(cv.z);
        hv.w = sigm(go.w) * tanhf(cv.w);
        ((float4*)h_lds)[idx4] = hv;
        if (blockIdx.x == 0) {
            ((float4*)hout)[idx4] = hv;
            ((float4*)cout)[idx4] = cv;
        }
        float sq = fmaf(hv.x, hv.x, fmaf(hv.y, hv.y, fmaf(hv.z, hv.z, hv.w * hv.w)));
#pragma unroll
        for (int off = 32; off; off >>= 1) sq += __shfl_xor(sq, off, 64);
        if (lane == 0) cpart[wave] = sq;
    }
    __syncthreads();
    const float K = sqrtf(cpart[0] + cpart[1] + cpart[2] + cpart[3]);  // ||h||_2

    float4 hr[4];
#pragma unroll
    for (int j = 0; j < 4; ++j) hr[j] = ((const float4*)h_lds)[lane + 64 * j];

    float maxl = -INFINITY, maxu = -INFINITY;
#pragma unroll
    for (int k = 0; k < RPW; ++k) {
        if (k + PF < RPW) wq[k + PF] = rb[(size_t)(k + PF) * 64];
        uint4 c = wq[k];
        float s = 0.f;
        {
            int v = (int)c.x;
            s = fmaf((float)((v << 24) >> 24), hr[0].x, s);
            s = fmaf((float)((v << 16) >> 24), hr[0].y, s);
            s = fmaf((float)((v << 8) >> 24),  hr[0].z, s);
            s = fmaf((float)(v >> 24),         hr[0].w, s);
        }
        {
            int v = (int)c.y;
            s = fmaf((float)((v << 24) >> 24), hr[1].x, s);
            s = fmaf((float)((v << 16) >> 24), hr[1].y, s);
            s = fmaf((float)((v << 8) >> 24),  hr[1].z, s);
            s = fmaf((float)(v >> 24),         hr[1].w, s);
        }
        {
            int v = (int)c.z;
            s = fmaf((float)((v << 24) >> 24), hr[2].x, s);
            s = fmaf((float)((v << 16) >> 24), hr[2].y, s);
            s = fmaf((float)((v << 8) >> 24),  hr[2].z, s);
            s = fmaf((float)(v >> 24),         hr[2].w, s);
        }
        {
            int v = (int)c.w;
            s = fmaf((float)((v << 24) >> 24), hr[3].x, s);
            s = fmaf((float)((v << 16) >> 24), hr[3].y, s);
            s = fmaf((float)((v << 8) >> 24),  hr[3].z, s);
            s = fmaf((float)(v >> 24),         hr[3].w, s);
        }
#pragma unroll
        for (int off = 32; off; off >>= 1) s += __shfl_xor(s, off, 64);
        int r = r0 + k;
        float4 snb = SNB[r];
        float L = fmaf(snb.x, s, snb.z);
        float e = fmaf(snb.y, K, 1e-6f);
        if (lane == 0) LE[r] = make_float2(L, e);
        maxl = fmaxf(maxl, L - e);
        maxu = fmaxf(maxu, L + e);
    }

    __shared__ float wl[8], wu[8];
    if (lane == 0) { wl[wave] = maxl; wu[wave] = maxu; }
    __syncthreads();
    if (tid == 0) {
        float lo = wl[0], up = wu[0];
        for (int w = 1; w < 8; ++w) { lo = fmaxf(lo, wl[w]); up = fmaxf(up, wu[w]); }
        pblock[blockIdx.x] = make_float2(lo, up);
    }
}

// ------- standalone tail finalize (last step only) -------
__global__ void finalize_tail_kernel(const float2* __restrict__ LE,
                                     const float2* __restrict__ pblock,
                                     const float* __restrict__ Wlin,
                                     const float* __restrict__ blin,
                                     const float* __restrict__ h,
                                     const float* __restrict__ emb,
                                     float* __restrict__ x, int* __restrict__ tok_out) {
    const int tid = threadIdx.x;              // 1024 threads
    const int lane = tid & 63, wv = tid >> 6; // 16 waves

    __shared__ float wmx[16];
    __shared__ float sM;
    __shared__ int snb, sncand, sovf;
    __shared__ int blist[BL_CAP];
    __shared__ int clist[CAND_CAP];

    float2 pb = make_float2(-INFINITY, -INFINITY);
    if (tid < NB_LOG) pb = pblock[tid];
    float m = pb.x;
#pragma unroll
    for (int off = 32; off; off >>= 1) m = fmaxf(m, __shfl_xor(m, off, 64));
    if (lane == 0) wmx[wv] = m;
    __syncthreads();
    if (tid == 0) {
        float M = wmx[0];
        for (int w = 1; w < 16; ++w) M = fmaxf(M, wmx[w]);
        sM = M; snb = 0; sncand = 0; sovf = 0;
    }
    __syncthreads();
    const float M = sM;

    if (tid < NB_LOG && pb.y >= M) {
        int p = atomicAdd(&snb, 1);
        if (p < BL_CAP) blist[p] = tid; else sovf = 1;
    }
    __syncthreads();
    if (!sovf) {
        int nb = snb < BL_CAP ? snb : BL_CAP;
        for (int ii = tid; ii < nb * RPB; ii += 1024) {
            int bi = ii / RPB, off = ii - bi * RPB;
            int r = blist[bi] * RPB + off;
            float2 le = LE[r];
            if (le.x + le.y >= M) {
                int p = atomicAdd(&sncand, 1);
                if (p < CAND_CAP) clist[p] = r; else sovf = 1;
            }
        }
    }
    __syncthreads();
    if (tid == 0 && sncand == 0) sovf = 1;
    __syncthreads();
    const int ovf = sovf;
    const int n = sncand < CAND_CAP ? sncand : CAND_CAP;

    float4 hr[4];
    load_h4(h, hr, lane);
    unsigned long long bestp = 0ull;
    if (!ovf) {
        for (int ci = wv; ci < n; ci += 16) {
            int row = clist[ci];
            float s = row_dot4(Wlin + (size_t)row * H_DIM, hr, lane) + blin[row];
            unsigned long long p = packmax(s, row);
            if (p > bestp) bestp = p;
        }
    } else {
        for (int row = wv; row < V_DIM; row += 16) {
            float s = row_dot4(Wlin + (size_t)row * H_DIM, hr, lane) + blin[row];
            unsigned long long p = packmax(s, row);
            if (p > bestp) bestp = p;
        }
    }
    __shared__ unsigned long long sbp[16];
    __shared__ int stok;
    if (lane == 0) sbp[wv] = bestp;
    __syncthreads();
    if (tid == 0) {
        unsigned long long B = sbp[0];
        for (int w = 1; w < 16; ++w) if (sbp[w] > B) B = sbp[w];
        int tok = (int)(0xFFFFFFFFu - (unsigned)(B & 0xFFFFFFFFu));
        stok = tok;
        *tok_out = tok;
    }
    __syncthreads();
    int tok = stok;
    if (tok < 0) tok = 0;
    if (tok >= V_DIM) tok = V_DIM - 1;
    const float4* e4 = (const float4*)(emb + (size_t)tok * E_DIM);
    float4* xo = (float4*)x;
    if (tid < E_DIM / 4) xo[tid] = e4[tid];
}

extern "C" void kernel_launch(void* const* d_in, const int* in_sizes, int n_in,
                              void* d_out, int out_size, void* d_ws, size_t ws_size,
                              hipStream_t stream) {
    const float* inp  = (const float*)d_in[0];
    const float* Wih  = (const float*)d_in[1];
    const float* Whh  = (const float*)d_in[2];
    const float* bih  = (const float*)d_in[3];
    const float* bhh  = (const float*)d_in[4];
    const float* emb  = (const float*)d_in[5];
    const float* Wlin = (const float*)d_in[6];
    const float* blin = (const float*)d_in[7];
    int* toks = (int*)d_out;

    char* ws = (char*)d_ws;
    float* x     = (float*)(ws + OFF_X);
    float* h     = (float*)(ws + OFF_H);
    float* c0b   = (float*)(ws + OFF_C);
    float* c1b   = (float*)(ws + OFF_C2);
    float* gates = (float*)(ws + OFF_GATES);
    float* hn    = (float*)(ws + OFF_HN);
    unsigned long long* partials = (unsigned long long*)(ws + OFF_PART);
    float2* pblock = (float2*)(ws + OFF_PBLOCK);
    float4* SNB  = (float4*)(ws + OFF_SNB);
    float2* LE   = (float2*)(ws + OFF_LE);
    uint4* WbI   = (uint4*)(ws + OFF_WBI);

    const int useI8 = (ws_size >= WS_NEEDED) ? 1 : 0;

    init_kernel<<<1, 1024, 0, stream>>>(inp, x, h, c0b, SNB);

    if (!useI8) {
        for (int step = 0; step < NSTEPS; ++step) {
            gatesfin_kernel<<<NB_GATES, 256, 0, stream>>>(
                Wih, Whh, bih, bhh, x, h, gates, LE, pblock, Wlin, blin, emb,
                (int*)nullptr, 0);
            cell_kernel<<<1, 1024, 0, stream>>>(gates, c0b, h, hn);
            logits_f32_kernel<<<NB_F32, 256, 0, stream>>>(
                Wlin, blin, h, WbI, SNB, 0, partials);
            finalize_f32_kernel<<<1, 256, 0, stream>>>(partials, emb, x, toks + step);
        }
        return;
    }

    // ---- step 0: fp32 exact scan + int8 conversion ----
    gatesfin_kernel<<<NB_GATES, 256, 0, stream>>>(
        Wih, Whh, bih, bhh, x, h, gates, LE, pblock, Wlin, blin, emb,
        (int*)nullptr, 0);
    cell_kernel<<<1, 1024, 0, stream>>>(gates, c0b, h, hn);
    logits_f32_kernel<<<NB_F32, 256, 0, stream>>>(
        Wlin, blin, h, WbI, SNB, 1, partials);
    finalize_f32_kernel<<<1, 256, 0, stream>>>(partials, emb, x, toks + 0);

    // ---- steps 1..18: 2 kernels per step ----
    for (int t = 1; t < NSTEPS; ++t) {
        gatesfin_kernel<<<NB_GATES, 256, 0, stream>>>(
            Wih, Whh, bih, bhh, x, h, gates, LE, pblock, Wlin, blin, emb,
            (t >= 2) ? (toks + t - 1) : (int*)nullptr, (t >= 2) ? 1 : 0);
        float* cin  = (t & 1) ? c0b : c1b;
        float* cout = (t & 1) ? c1b : c0b;
        logits_i8_kernel<<<NB_LOG, 512, 0, stream>>>(
            WbI, SNB, gates, cin, cout, h, LE, pblock);
    }
    // tail: finalize step 18
    finalize_tail_kernel<<<1, 1024, 0, stream>>>(LE, pblock, Wlin, blin, h, emb,
                                                 x, toks + NSTEPS - 1);
}